// Round 7
// baseline (116.391 us; speedup 1.0000x reference)
//
#include <hip/hip_runtime.h>

// DecoderLayer: out[k,n,m] = tanh(sum_p w[k,p]*prev[idx[k,p],n,m] + b[k]),
// gated by (#active parents >= 12).  M=2048, K=4096, NN=4096 (64x64), P=16.
//
// R7: LDS abandoned (measured: LDS pipe = 84% of kernel at ~45cyc/gather,
// floor 20us even conflict-free). Gather straight from global: per-block
// working set is prev[:,pos0:pos0+16] = 128KB -> L2-resident. Lane-quads per
// node keep each wave-gather = 16 full 64B lines. No LDS, no barriers ->
// 32 waves/CU, 1024 blocks in one round. XCD swizzle: 4 quarter-blocks of a
// tile + 32 neighbor tiles per XCD = 4MB slice set = one XCD's L2.

#define M_ROWS   2048
#define K_NODES  4096
#define NN       4096
#define POS_TILE 16
#define NTHREADS 512
#define OUT_ELEMS (K_NODES * NN)
#define ACTIVE_THRESHOLD 12

typedef float f32x4 __attribute__((ext_vector_type(4)));

__device__ __forceinline__ float fast_tanh(float x) {
  float ax = __builtin_fabsf(x);
  float e  = __expf(-2.0f * ax);
  float r  = (1.0f - e) * __builtin_amdgcn_rcpf(1.0f + e);
  return __builtin_copysignf(r, x);
}

// Gate precompute (off hot path). Runtime-detects isact marshaling:
// any 32-bit word >1 in the first 2048 bytes implies packed bytes.
__global__ __launch_bounds__(256) void act_kernel(
    const int* __restrict__ pidx, const unsigned int* __restrict__ isact,
    float* __restrict__ outact) {
  __shared__ int mode_sh;
  if (threadIdx.x == 0) mode_sh = 0;
  __syncthreads();
  int bad = 0;
  for (int i = threadIdx.x; i < 512; i += 256) bad |= (isact[i] > 1u);
  if (bad) atomicOr(&mode_sh, 1);
  __syncthreads();
  const int shift = mode_sh ? 0 : 2;   // LSB byte of a 0/1 int32 == its value
  const unsigned char* actb = (const unsigned char*)isact;

  int k = blockIdx.x * 256 + threadIdx.x;
  const int4* ip = (const int4*)(pidx + k * 16);
  int4 ia = ip[0], ib = ip[1], ic = ip[2], id4 = ip[3];
  int ids[16] = {ia.x, ia.y, ia.z, ia.w, ib.x, ib.y, ib.z, ib.w,
                 ic.x, ic.y, ic.z, ic.w, id4.x, id4.y, id4.z, id4.w};
  int n = 0;
  #pragma unroll
  for (int p = 0; p < 16; ++p) n += (actb[ids[p] << shift] != 0);
  outact[k] = (n >= ACTIVE_THRESHOLD) ? 1.0f : 0.0f;
}

__global__ __launch_bounds__(NTHREADS, 8) void decoder_kernel(
    const float* __restrict__ prev, const int* __restrict__ pidx,
    const float* __restrict__ w, const float* __restrict__ b,
    const float* __restrict__ actf, float* __restrict__ out) {
  const int tid = threadIdx.x;
  const int bid = blockIdx.x;              // 0..1023
  // bid%8 -> XCD (dispatch round-robin). Each XCD owns 32 consecutive tiles;
  // the 4 quarter-blocks of a tile are consecutive j on the same XCD.
  const int xcd     = bid & 7;
  const int j       = bid >> 3;            // 0..127
  const int tile    = xcd * 32 + (j >> 2); // 0..255
  const int quarter = j & 3;
  const int pos0    = tile * POS_TILE;

  const int q  = tid & 3;                  // 16B chunk this lane owns
  const int nq = tid >> 2;                 // node-quad, 0..127
  const int n0 = quarter * (K_NODES / 4);

  // f32x4-typed base: lane's fixed 16B column chunk; row stride = 1024 chunks
  const f32x4* __restrict__ base = (const f32x4*)(prev + pos0 + (q << 2));

  for (int it = 0; it < 8; ++it) {
    int n = n0 + (it << 7) + nq;
    const int4*   ip = (const int4*)(pidx + (n << 4));
    const float4* wp = (const float4*)(w + (n << 4));
    float bk = b[n];
    float g  = actf[n];                    // 0.0 / 1.0

    f32x4 A0 = {bk, bk, bk, bk}, A1 = {0.f, 0.f, 0.f, 0.f};

    // 4 batches of 4 parents: 4 gathers (16 L2 lines each) in flight,
    // VGPR stays under the 64-reg / 8-wave-per-EU cap.
    #pragma unroll
    for (int bb = 0; bb < 4; ++bb) {
      int4   iv = ip[bb];
      float4 wv = wp[bb];
      f32x4 x0 = base[(size_t)iv.x << 10];
      f32x4 x1 = base[(size_t)iv.y << 10];
      f32x4 x2 = base[(size_t)iv.z << 10];
      f32x4 x3 = base[(size_t)iv.w << 10];
      A0 += wv.x * x0;  A1 += wv.y * x1;
      A0 += wv.z * x2;  A1 += wv.w * x3;
    }

    f32x4 acc = A0 + A1;
    f32x4 o;
    o.x = fast_tanh(acc.x) * g;
    o.y = fast_tanh(acc.y) * g;
    o.z = fast_tanh(acc.z) * g;
    o.w = fast_tanh(acc.w) * g;
    // quad writes one contiguous 64B line of out row n
    *(f32x4*)(out + (size_t)n * NN + pos0 + (q << 2)) = o;
  }
}

extern "C" void kernel_launch(void* const* d_in, const int* in_sizes, int n_in,
                              void* d_out, int out_size, void* d_ws, size_t ws_size,
                              hipStream_t stream) {
  const float* prev  = (const float*)d_in[0];
  const void*  isact = d_in[1];
  const int*   pidx  = (const int*)d_in[2];
  const float* w     = (const float*)d_in[3];
  const float* b     = (const float*)d_in[4];
  float* out    = (float*)d_out;
  float* outact = out + OUT_ELEMS;

  act_kernel<<<K_NODES / 256, 256, 0, stream>>>(
      pidx, (const unsigned int*)isact, outact);
  decoder_kernel<<<(NN / POS_TILE) * 4, NTHREADS, 0, stream>>>(
      prev, pidx, w, b, outact, out);
}